// Round 4
// baseline (547.809 us; speedup 1.0000x reference)
//
#include <hip/hip_runtime.h>
#include <math.h>

#define N_NODES 50000
#define N_EDGES 800000
#define D 128          // NODE_DIM
#define DE 10          // EDGE_DIM
#define K_TOT 266      // 2*D + DE
#define TE 64          // edges per block (CSR-consecutive)
#define ZSTRIDE 296    // bf16 per z row in LDS (288 + 8 pad, 16B-aligned)
#define MSTRIDE 129    // f32 per m row in LDS epilogue buffer
#define WP_ELEMS (9 * 16 * 64 * 8)   // packed weight elements (bf16) = 73728

typedef __bf16 bf16x8 __attribute__((ext_vector_type(8)));
typedef __bf16 bf16x4 __attribute__((ext_vector_type(4)));
typedef float  f32x4  __attribute__((ext_vector_type(4)));

// Single-HW-instruction transcendentals (v_exp_f32 / v_log_f32 / v_rcp_f32).
__device__ __forceinline__ float fast_sigmoid(float x) {
    float t = __builtin_amdgcn_exp2f(-1.44269504089f * x);
    return __builtin_amdgcn_rcpf(1.0f + t);
}
__device__ __forceinline__ float fast_softplus(float x) {
    float t = __builtin_amdgcn_exp2f(-1.44269504089f * fabsf(x));
    return fmaxf(x, 0.0f) + 0.69314718056f * __builtin_amdgcn_logf(1.0f + t);
}

// ---- fused prep: cvt h->bf16 | pack weights | zero CSR counts ----
// blocks [0,6250): cvt_h (1.6M float4)
// blocks [6250,6538): pack_weights (73728 elems)
// blocks [6538,6734): zero counts (50000 ints)
__global__ __launch_bounds__(256) void prep(
    const float* __restrict__ h, const float* __restrict__ gw,
    const float* __restrict__ cw, __bf16* __restrict__ hb,
    __bf16* __restrict__ wp, int* __restrict__ counts)
{
    int bx = blockIdx.x, t = threadIdx.x;
    if (bx < 6250) {
        int i4 = bx * 256 + t;
        float4 v = *(const float4*)&h[(size_t)i4 * 4];
        bf16x4 o = { (__bf16)v.x, (__bf16)v.y, (__bf16)v.z, (__bf16)v.w };
        *(bf16x4*)&hb[(size_t)i4 * 4] = o;
    } else if (bx < 6538) {
        int idx = (bx - 6250) * 256 + t;
        if (idx < WP_ELEMS) {
            int j    = idx & 7;
            int lane = (idx >> 3) & 63;
            int nb   = (idx >> 9) & 15;
            int kb   = idx >> 13;
            int k    = kb * 32 + ((lane >> 4) << 3) + j;
            int col  = ((nb >> 1) << 4) + (lane & 15);
            const float* w = (nb & 1) ? cw : gw;
            float v = (k < K_TOT) ? w[k * D + col] : 0.0f;
            wp[idx] = (__bf16)v;
        }
    } else {
        int n = (bx - 6538) * 256 + t;
        if (n < N_NODES) counts[n] = 0;
    }
}

// ---- CSR build ----
__global__ __launch_bounds__(256) void csr_hist(
    const int* __restrict__ ei, int* __restrict__ counts)
{
    int e = blockIdx.x * 256 + threadIdx.x;   // grid exact: 800000
    atomicAdd(&counts[ei[e]], 1);
}

__global__ __launch_bounds__(256) void csr_scan(
    const int* __restrict__ counts, int* __restrict__ offsets,
    int* __restrict__ cursor)
{
    __shared__ int ssum[256];
    const int tid = threadIdx.x;
    const int CH = 196;                        // 256*196 = 50176 >= 50000
    int lo = tid * CH, hi = min(lo + CH, N_NODES);
    int s = 0;
    for (int n = lo; n < hi; ++n) s += counts[n];
    ssum[tid] = s;
    __syncthreads();
    for (int off = 1; off < 256; off <<= 1) {
        int v = (tid >= off) ? ssum[tid - off] : 0;
        __syncthreads();
        ssum[tid] += v;
        __syncthreads();
    }
    int run = tid ? ssum[tid - 1] : 0;
    for (int n = lo; n < hi; ++n) {
        offsets[n] = run; cursor[n] = run;
        run += counts[n];
    }
    if (tid == 255) offsets[N_NODES] = run;
}

__global__ __launch_bounds__(256) void csr_scatter(
    const int* __restrict__ ei, int* __restrict__ cursor,
    int* __restrict__ eidx)
{
    int e = blockIdx.x * 256 + threadIdx.x;   // grid exact: 800000
    int pos = atomicAdd(&cursor[ei[e]], 1);
    eidx[pos] = e;
}

// ---- main: per CSR-ordered 64-edge tile: stage z, MFMA, LDS-reduce runs,
//      one atomic per distinct (node,col) per tile (~8M total vs 102.4M) ----
__global__ __launch_bounds__(256, 4) void edge_mfma_scatter(
    const __bf16* __restrict__ hb, const int* __restrict__ ei,
    const float* __restrict__ ef, const __bf16* __restrict__ wp,
    const float* __restrict__ gb, const float* __restrict__ cb,
    const int* __restrict__ eidx, float* __restrict__ agg)
{
    __shared__ __align__(16) unsigned char smem[TE * ZSTRIDE * 2]; // 37,888 B
    __shared__ int s_eid[TE], s_src[TE], s_dst[TE];
    __bf16* zs = (__bf16*)smem;
    float*  ms = (float*)smem;       // reused after MFMA (64 x MSTRIDE f32)

    const int t  = threadIdx.x;
    const int e0 = blockIdx.x * TE;

    if (t < TE) {
        int eid = eidx[e0 + t];
        s_eid[t] = eid;
        s_src[t] = ei[eid];
        s_dst[t] = ei[N_EDGES + eid];
    }
    __syncthreads();

    // ---- stage z tile (bf16): h[src] rows 0..127, h[dst] 128..255 ----
    #pragma unroll
    for (int it = 0; it < 8; ++it) {
        int lin = it * 256 + t;
        int region = lin >> 10;            // 0 = src, 1 = dst
        int r   = (lin >> 4) & 63;
        int seg = lin & 15;
        int node = region ? s_dst[r] : s_src[r];
        bf16x8 v = *(const bf16x8*)&hb[(size_t)node * D + seg * 8];
        *(bf16x8*)&zs[r * ZSTRIDE + region * 128 + seg * 8] = v;
    }
    // k 256..287: edge_feat (10 fp32 -> bf16) + zero pad (22)
    #pragma unroll
    for (int it = 0; it < 8; ++it) {
        int lin = it * 256 + t;
        int e   = lin >> 5;
        int kk  = lin & 31;
        float v = (kk < DE) ? ef[(size_t)s_eid[e] * DE + kk] : 0.0f;
        zs[e * ZSTRIDE + 256 + kk] = (__bf16)v;
    }
    __syncthreads();

    // ---- MFMA: [64 x 288] @ [288 x 256] ----
    const int w     = t >> 6;
    const int l     = t & 63;
    const int quad  = l >> 4;
    const int col16 = l & 15;

    f32x4 acc[4][4];
    #pragma unroll
    for (int mt = 0; mt < 4; ++mt)
        #pragma unroll
        for (int nt = 0; nt < 4; ++nt)
            acc[mt][nt] = (f32x4)0.0f;

    const __bf16* zp  = &zs[col16 * ZSTRIDE + quad * 8];
    const __bf16* wpp = &wp[(size_t)((w * 4) * 64 + l) * 8];

    #pragma unroll
    for (int kb = 0; kb < 9; ++kb) {
        bf16x8 afr[4];
        #pragma unroll
        for (int mt = 0; mt < 4; ++mt)
            afr[mt] = *(const bf16x8*)&zp[mt * 16 * ZSTRIDE + kb * 32];
        bf16x8 bfr[4];
        #pragma unroll
        for (int nt = 0; nt < 4; ++nt)
            bfr[nt] = *(const bf16x8*)&wpp[(size_t)(kb * 16 + nt) * 512];
        #pragma unroll
        for (int mt = 0; mt < 4; ++mt)
            #pragma unroll
            for (int nt = 0; nt < 4; ++nt)
                acc[mt][nt] = __builtin_amdgcn_mfma_f32_16x16x32_bf16(
                    afr[mt], bfr[nt], acc[mt][nt], 0, 0, 0);
    }
    __syncthreads();   // all waves done reading zs; safe to overwrite as ms

    // ---- m = sigmoid(g+gb)*softplus(c+cb) -> LDS ----
    const int colA = w * 32 + col16;
    const int colB = colA + 16;
    const float gbA = gb[colA], cbA = cb[colA];
    const float gbB = gb[colB], cbB = cb[colB];

    #pragma unroll
    for (int mt = 0; mt < 4; ++mt) {
        #pragma unroll
        for (int r = 0; r < 4; ++r) {
            int e = mt * 16 + quad * 4 + r;
            ms[e * MSTRIDE + colA] =
                fast_sigmoid(acc[mt][0][r] + gbA) * fast_softplus(acc[mt][1][r] + cbA);
            ms[e * MSTRIDE + colB] =
                fast_sigmoid(acc[mt][2][r] + gbB) * fast_softplus(acc[mt][3][r] + cbB);
        }
    }
    __syncthreads();

    // ---- run-segmented reduction over CSR-sorted rows, one atomic per run ----
    const int half = t >> 7;           // rows [half*32, half*32+32)
    const int c    = t & 127;
    const int rlo  = half * 32, rhi = rlo + 32;
    int   cur = s_src[rlo];
    float s   = 0.0f;
    for (int e = rlo; e < rhi; ++e) {
        int node = s_src[e];
        float v  = ms[e * MSTRIDE + c];
        if (node != cur) {
            atomicAdd(&agg[(size_t)cur * D + c], s);
            s = 0.0f; cur = node;
        }
        s += v;
    }
    atomicAdd(&agg[(size_t)cur * D + c], s);
}

__global__ __launch_bounds__(256) void col_stats(
    const float* __restrict__ agg, float* __restrict__ stats)
{
    const int t    = threadIdx.x;
    const int col  = t & 127;
    const int half = t >> 7;
    float s = 0.0f, s2 = 0.0f;
    for (int r = blockIdx.x * 2 + half; r < N_NODES; r += gridDim.x * 2) {
        float v = agg[(size_t)r * D + col];
        s += v; s2 += v * v;
    }
    atomicAdd(&stats[col], s);
    atomicAdd(&stats[128 + col], s2);
}

__global__ void finalize_stats(
    const float* __restrict__ stats, const float* __restrict__ gamma,
    const float* __restrict__ beta, float* __restrict__ scbi)
{
    int c = threadIdx.x;              // 128 threads
    const float inv_n = 1.0f / (float)N_NODES;
    float mean = stats[c] * inv_n;
    float var  = stats[128 + c] * inv_n - mean * mean;
    var = fmaxf(var, 0.0f);
    float rstd = rsqrtf(var + 1e-5f);
    float sc = rstd * gamma[c];
    scbi[c]       = sc;
    scbi[128 + c] = beta[c] - mean * sc;
}

__global__ __launch_bounds__(256) void out_softplus(
    const float* __restrict__ h, const float* __restrict__ agg,
    const float* __restrict__ scbi, float* __restrict__ out)
{
    __shared__ float sc[128], bi[128];
    int t = threadIdx.x;
    if (t < 128) { sc[t] = scbi[t]; bi[t] = scbi[128 + t]; }
    __syncthreads();
    int idx4 = blockIdx.x * 256 + t;
    int base = idx4 * 4;
    if (base < N_NODES * D) {
        float4 hv = *(const float4*)&h[base];
        float4 av = *(const float4*)&agg[base];
        int c = base & 127;
        float4 o;
        o.x = fast_softplus(hv.x + av.x * sc[c + 0] + bi[c + 0]);
        o.y = fast_softplus(hv.y + av.y * sc[c + 1] + bi[c + 1]);
        o.z = fast_softplus(hv.z + av.z * sc[c + 2] + bi[c + 2]);
        o.w = fast_softplus(hv.w + av.w * sc[c + 3] + bi[c + 3]);
        *(float4*)&out[base] = o;
    }
}

extern "C" void kernel_launch(void* const* d_in, const int* in_sizes, int n_in,
                              void* d_out, int out_size, void* d_ws, size_t ws_size,
                              hipStream_t stream) {
    const float* h     = (const float*)d_in[0];
    const int*   ei    = (const int*)  d_in[1];
    const float* ef    = (const float*)d_in[2];
    const float* gw    = (const float*)d_in[3];
    const float* gb    = (const float*)d_in[4];
    const float* cw    = (const float*)d_in[5];
    const float* cb    = (const float*)d_in[6];
    const float* gamma = (const float*)d_in[7];
    const float* beta  = (const float*)d_in[8];
    float* out = (float*)d_out;

    float*  agg     = (float*)d_ws;                       // 25.6 MB
    float*  stats   = agg + (size_t)N_NODES * D;          // 256 f
    float*  scbi    = stats + 256;                        // 256 f
    __bf16* wp      = (__bf16*)(scbi + 256);              // 144 KB
    __bf16* hb      = wp + WP_ELEMS;                      // 12.8 MB
    int*    counts  = (int*)(hb + (size_t)N_NODES * D);   // 200 KB
    int*    offsets = counts + N_NODES;                   // 50001 ints
    int*    cursor  = offsets + N_NODES + 1;              // 50000 ints
    int*    eidx    = cursor + N_NODES;                   // 3.2 MB
    // total ~42.4 MB (< 55 MB proven in prior rounds)

    hipMemsetAsync(d_ws, 0, ((size_t)N_NODES * D + 512) * sizeof(float), stream);
    prep<<<6734, 256, 0, stream>>>(h, gw, cw, hb, wp, counts);
    csr_hist<<<N_EDGES / 256, 256, 0, stream>>>(ei, counts);
    csr_scan<<<1, 256, 0, stream>>>(counts, offsets, cursor);
    csr_scatter<<<N_EDGES / 256, 256, 0, stream>>>(ei, cursor, eidx);
    edge_mfma_scatter<<<N_EDGES / TE, 256, 0, stream>>>(hb, ei, ef, wp, gb, cb, eidx, agg);
    col_stats<<<200, 256, 0, stream>>>(agg, stats);
    finalize_stats<<<1, 128, 0, stream>>>(stats, gamma, beta, scbi);
    out_softplus<<<(N_NODES * D / 4 + 255) / 256, 256, 0, stream>>>(h, agg, scbi, out);
}

// Round 5
// 415.248 us; speedup vs baseline: 1.3192x; 1.3192x over previous
//
#include <hip/hip_runtime.h>
#include <math.h>

#define N_NODES 50000
#define N_EDGES 800000
#define D 128          // NODE_DIM
#define DE 10          // EDGE_DIM
#define K_TOT 266      // 2*D + DE
#define TE 64          // edges per block (CSR-consecutive)
#define ZSTRIDE 296    // bf16 per z row in LDS (288 + 8 pad; 592B row = 2-way bank alias = free)
#define MSTRIDE 129    // f32 per m row in LDS epilogue buffer
#define WP_ELEMS (9 * 16 * 64 * 8)   // packed weight elements (bf16) = 73728
#define SCAN_BLOCKS 196              // 196*256 = 50176 >= 50000

typedef __bf16 bf16x8 __attribute__((ext_vector_type(8)));
typedef __bf16 bf16x4 __attribute__((ext_vector_type(4)));
typedef __bf16 bf16x2 __attribute__((ext_vector_type(2)));
typedef float  f32x4  __attribute__((ext_vector_type(4)));

// Single-HW-instruction transcendentals (v_exp_f32 / v_log_f32 / v_rcp_f32).
__device__ __forceinline__ float fast_sigmoid(float x) {
    float t = __builtin_amdgcn_exp2f(-1.44269504089f * x);
    return __builtin_amdgcn_rcpf(1.0f + t);
}
__device__ __forceinline__ float fast_softplus(float x) {
    float t = __builtin_amdgcn_exp2f(-1.44269504089f * fabsf(x));
    return fmaxf(x, 0.0f) + 0.69314718056f * __builtin_amdgcn_logf(1.0f + t);
}

// ---- fused prep: cvt h->bf16 | pack weights | zero CSR counts ----
__global__ __launch_bounds__(256) void prep(
    const float* __restrict__ h, const float* __restrict__ gw,
    const float* __restrict__ cw, __bf16* __restrict__ hb,
    __bf16* __restrict__ wp, int* __restrict__ counts)
{
    int bx = blockIdx.x, t = threadIdx.x;
    if (bx < 6250) {
        int i4 = bx * 256 + t;
        float4 v = *(const float4*)&h[(size_t)i4 * 4];
        bf16x4 o = { (__bf16)v.x, (__bf16)v.y, (__bf16)v.z, (__bf16)v.w };
        *(bf16x4*)&hb[(size_t)i4 * 4] = o;
    } else if (bx < 6538) {
        int idx = (bx - 6250) * 256 + t;
        if (idx < WP_ELEMS) {
            int j    = idx & 7;
            int lane = (idx >> 3) & 63;
            int nb   = (idx >> 9) & 15;
            int kb   = idx >> 13;
            int k    = kb * 32 + ((lane >> 4) << 3) + j;
            int col  = ((nb >> 1) << 4) + (lane & 15);
            const float* w = (nb & 1) ? cw : gw;
            float v = (k < K_TOT) ? w[k * D + col] : 0.0f;
            wp[idx] = (__bf16)v;
        }
    } else {
        int n = (bx - 6538) * 256 + t;
        if (n < N_NODES) counts[n] = 0;
    }
}

// ---- CSR build: hist -> parallel 3-phase scan -> scatter ----
__global__ __launch_bounds__(256) void csr_hist(
    const int* __restrict__ ei, int* __restrict__ counts)
{
    int e = blockIdx.x * 256 + threadIdx.x;   // grid exact: 800000
    atomicAdd(&counts[ei[e]], 1);
}

// Phase 1: per-block sums of 256 counts
__global__ __launch_bounds__(256) void scan_partials(
    const int* __restrict__ counts, int* __restrict__ bsum)
{
    __shared__ int ss[256];
    int t = threadIdx.x;
    int i = blockIdx.x * 256 + t;
    int c = (i < N_NODES) ? counts[i] : 0;
    ss[t] = c;
    __syncthreads();
    #pragma unroll
    for (int off = 1; off < 256; off <<= 1) {
        int v = (t >= off) ? ss[t - off] : 0;
        __syncthreads();
        ss[t] += v;
        __syncthreads();
    }
    if (t == 255) bsum[blockIdx.x] = ss[255];
}

// Phase 2: single-block exclusive scan of the 196 block sums
__global__ __launch_bounds__(256) void scan_top(
    const int* __restrict__ bsum, int* __restrict__ bbase)
{
    __shared__ int ss[256];
    int t = threadIdx.x;
    int v = (t < SCAN_BLOCKS) ? bsum[t] : 0;
    ss[t] = v;
    __syncthreads();
    #pragma unroll
    for (int off = 1; off < 256; off <<= 1) {
        int u = (t >= off) ? ss[t - off] : 0;
        __syncthreads();
        ss[t] += u;
        __syncthreads();
    }
    if (t < SCAN_BLOCKS) bbase[t] = ss[t] - v;   // exclusive
}

// Phase 3: block-local exclusive scan + block base -> cursor
__global__ __launch_bounds__(256) void scan_final(
    const int* __restrict__ counts, const int* __restrict__ bbase,
    int* __restrict__ cursor)
{
    __shared__ int ss[256];
    int t = threadIdx.x;
    int i = blockIdx.x * 256 + t;
    int c = (i < N_NODES) ? counts[i] : 0;
    ss[t] = c;
    __syncthreads();
    #pragma unroll
    for (int off = 1; off < 256; off <<= 1) {
        int v = (t >= off) ? ss[t - off] : 0;
        __syncthreads();
        ss[t] += v;
        __syncthreads();
    }
    if (i < N_NODES) cursor[i] = bbase[blockIdx.x] + ss[t] - c;
}

__global__ __launch_bounds__(256) void csr_scatter(
    const int* __restrict__ ei, int* __restrict__ cursor,
    int* __restrict__ eidx)
{
    int e = blockIdx.x * 256 + threadIdx.x;   // grid exact: 800000
    int pos = atomicAdd(&cursor[ei[e]], 1);
    eidx[pos] = e;
}

// ---- main: per CSR-ordered 64-edge tile: stage z, MFMA, LDS-reduce runs,
//      one atomic per distinct (node,col) per tile (~8M vs 102.4M naive) ----
__global__ __launch_bounds__(256, 4) void edge_mfma_scatter(
    const __bf16* __restrict__ hb, const int* __restrict__ ei,
    const float* __restrict__ ef, const __bf16* __restrict__ wp,
    const float* __restrict__ gb, const float* __restrict__ cb,
    const int* __restrict__ eidx, float* __restrict__ agg)
{
    __shared__ __align__(16) unsigned char smem[TE * ZSTRIDE * 2]; // 37,888 B
    __shared__ int s_eid[TE], s_src[TE], s_dst[TE];
    __bf16* zs = (__bf16*)smem;
    float*  ms = (float*)smem;       // reused after MFMA (64 x MSTRIDE f32)

    const int t  = threadIdx.x;
    const int e0 = blockIdx.x * TE;

    if (t < TE) {
        int eid = eidx[e0 + t];
        s_eid[t] = eid;
        s_src[t] = ei[eid];
        s_dst[t] = ei[N_EDGES + eid];
    }
    __syncthreads();

    // ---- stage z tile (bf16): h[src] rows k=0..127, h[dst] k=128..255 ----
    #pragma unroll
    for (int it = 0; it < 8; ++it) {
        int lin = it * 256 + t;
        int region = lin >> 10;            // 0 = src, 1 = dst
        int r   = (lin >> 4) & 63;
        int seg = lin & 15;
        int node = region ? s_dst[r] : s_src[r];
        bf16x8 v = *(const bf16x8*)&hb[(size_t)node * D + seg * 8];
        *(bf16x8*)&zs[r * ZSTRIDE + region * 128 + seg * 8] = v;
    }
    // k 256..287: edge_feat (10 fp32, vectorized float2 x5) + zero pad (22)
    if (t < TE) {
        const float* efr = &ef[(size_t)s_eid[t] * DE];   // 8B-aligned (40B rows)
        __bf16* row = &zs[t * ZSTRIDE + 256];
        #pragma unroll
        for (int j = 0; j < 5; ++j) {
            float2 a = *(const float2*)&efr[j * 2];
            bf16x2 p = { (__bf16)a.x, (__bf16)a.y };
            *(bf16x2*)&row[j * 2] = p;
        }
        *(bf16x2*)&row[10] = (bf16x2)(__bf16)0.0f;
        *(bf16x4*)&row[12] = (bf16x4)(__bf16)0.0f;
        *(bf16x8*)&row[16] = (bf16x8)(__bf16)0.0f;
        *(bf16x8*)&row[24] = (bf16x8)(__bf16)0.0f;
    }
    __syncthreads();

    // ---- MFMA: [64 x 288] @ [288 x 256] ----
    const int w     = t >> 6;
    const int l     = t & 63;
    const int quad  = l >> 4;
    const int col16 = l & 15;

    f32x4 acc[4][4];
    #pragma unroll
    for (int mt = 0; mt < 4; ++mt)
        #pragma unroll
        for (int nt = 0; nt < 4; ++nt)
            acc[mt][nt] = (f32x4)0.0f;

    const __bf16* zp  = &zs[col16 * ZSTRIDE + quad * 8];
    const __bf16* wpp = &wp[(size_t)((w * 4) * 64 + l) * 8];

    #pragma unroll
    for (int kb = 0; kb < 9; ++kb) {
        bf16x8 afr[4];
        #pragma unroll
        for (int mt = 0; mt < 4; ++mt)
            afr[mt] = *(const bf16x8*)&zp[mt * 16 * ZSTRIDE + kb * 32];
        bf16x8 bfr[4];
        #pragma unroll
        for (int nt = 0; nt < 4; ++nt)
            bfr[nt] = *(const bf16x8*)&wpp[(size_t)(kb * 16 + nt) * 512];
        #pragma unroll
        for (int mt = 0; mt < 4; ++mt)
            #pragma unroll
            for (int nt = 0; nt < 4; ++nt)
                acc[mt][nt] = __builtin_amdgcn_mfma_f32_16x16x32_bf16(
                    afr[mt], bfr[nt], acc[mt][nt], 0, 0, 0);
    }
    __syncthreads();   // all waves done reading zs; safe to overwrite as ms

    // ---- m = sigmoid(g+gb)*softplus(c+cb) -> LDS ----
    const int colA = w * 32 + col16;
    const int colB = colA + 16;
    const float gbA = gb[colA], cbA = cb[colA];
    const float gbB = gb[colB], cbB = cb[colB];

    #pragma unroll
    for (int mt = 0; mt < 4; ++mt) {
        #pragma unroll
        for (int r = 0; r < 4; ++r) {
            int e = mt * 16 + quad * 4 + r;
            ms[e * MSTRIDE + colA] =
                fast_sigmoid(acc[mt][0][r] + gbA) * fast_softplus(acc[mt][1][r] + cbA);
            ms[e * MSTRIDE + colB] =
                fast_sigmoid(acc[mt][2][r] + gbB) * fast_softplus(acc[mt][3][r] + cbB);
        }
    }
    __syncthreads();

    // ---- run-segmented reduction over CSR-sorted rows, one atomic per run ----
    const int half = t >> 7;           // rows [half*32, half*32+32)
    const int c    = t & 127;
    const int rlo  = half * 32, rhi = rlo + 32;
    int   cur = s_src[rlo];
    float s   = 0.0f;
    for (int e = rlo; e < rhi; ++e) {
        int node = s_src[e];
        float v  = ms[e * MSTRIDE + c];
        if (node != cur) {
            atomicAdd(&agg[(size_t)cur * D + c], s);
            s = 0.0f; cur = node;
        }
        s += v;
    }
    atomicAdd(&agg[(size_t)cur * D + c], s);
}

__global__ __launch_bounds__(256) void col_stats(
    const float* __restrict__ agg, float* __restrict__ stats)
{
    const int t    = threadIdx.x;
    const int col  = t & 127;
    const int half = t >> 7;
    float s = 0.0f, s2 = 0.0f;
    for (int r = blockIdx.x * 2 + half; r < N_NODES; r += gridDim.x * 2) {
        float v = agg[(size_t)r * D + col];
        s += v; s2 += v * v;
    }
    atomicAdd(&stats[col], s);
    atomicAdd(&stats[128 + col], s2);
}

__global__ void finalize_stats(
    const float* __restrict__ stats, const float* __restrict__ gamma,
    const float* __restrict__ beta, float* __restrict__ scbi)
{
    int c = threadIdx.x;              // 128 threads
    const float inv_n = 1.0f / (float)N_NODES;
    float mean = stats[c] * inv_n;
    float var  = stats[128 + c] * inv_n - mean * mean;
    var = fmaxf(var, 0.0f);
    float rstd = rsqrtf(var + 1e-5f);
    float sc = rstd * gamma[c];
    scbi[c]       = sc;
    scbi[128 + c] = beta[c] - mean * sc;
}

__global__ __launch_bounds__(256) void out_softplus(
    const float* __restrict__ h, const float* __restrict__ agg,
    const float* __restrict__ scbi, float* __restrict__ out)
{
    __shared__ float sc[128], bi[128];
    int t = threadIdx.x;
    if (t < 128) { sc[t] = scbi[t]; bi[t] = scbi[128 + t]; }
    __syncthreads();
    int idx4 = blockIdx.x * 256 + t;
    int base = idx4 * 4;
    if (base < N_NODES * D) {
        float4 hv = *(const float4*)&h[base];
        float4 av = *(const float4*)&agg[base];
        int c = base & 127;
        float4 o;
        o.x = fast_softplus(hv.x + av.x * sc[c + 0] + bi[c + 0]);
        o.y = fast_softplus(hv.y + av.y * sc[c + 1] + bi[c + 1]);
        o.z = fast_softplus(hv.z + av.z * sc[c + 2] + bi[c + 2]);
        o.w = fast_softplus(hv.w + av.w * sc[c + 3] + bi[c + 3]);
        *(float4*)&out[base] = o;
    }
}

extern "C" void kernel_launch(void* const* d_in, const int* in_sizes, int n_in,
                              void* d_out, int out_size, void* d_ws, size_t ws_size,
                              hipStream_t stream) {
    const float* h     = (const float*)d_in[0];
    const int*   ei    = (const int*)  d_in[1];
    const float* ef    = (const float*)d_in[2];
    const float* gw    = (const float*)d_in[3];
    const float* gb    = (const float*)d_in[4];
    const float* cw    = (const float*)d_in[5];
    const float* cb    = (const float*)d_in[6];
    const float* gamma = (const float*)d_in[7];
    const float* beta  = (const float*)d_in[8];
    float* out = (float*)d_out;

    float*  agg     = (float*)d_ws;                       // 25.6 MB
    float*  stats   = agg + (size_t)N_NODES * D;          // 256 f
    float*  scbi    = stats + 256;                        // 256 f
    __bf16* wp      = (__bf16*)(scbi + 256);              // 144 KB
    __bf16* hb      = wp + WP_ELEMS;                      // 12.8 MB
    int*    counts  = (int*)(hb + (size_t)N_NODES * D);   // 200 KB
    int*    cursor  = counts + N_NODES;                   // 200 KB
    int*    bsum    = cursor + N_NODES;                   // 256 ints
    int*    bbase   = bsum + 256;                         // 256 ints
    int*    eidx    = bbase + 256;                        // 3.2 MB
    // total ~42.2 MB (well within proven ws bounds)

    hipMemsetAsync(d_ws, 0, ((size_t)N_NODES * D + 512) * sizeof(float), stream);
    prep<<<6734, 256, 0, stream>>>(h, gw, cw, hb, wp, counts);
    csr_hist<<<N_EDGES / 256, 256, 0, stream>>>(ei, counts);
    scan_partials<<<SCAN_BLOCKS, 256, 0, stream>>>(counts, bsum);
    scan_top<<<1, 256, 0, stream>>>(bsum, bbase);
    scan_final<<<SCAN_BLOCKS, 256, 0, stream>>>(counts, bbase, cursor);
    csr_scatter<<<N_EDGES / 256, 256, 0, stream>>>(ei, cursor, eidx);
    edge_mfma_scatter<<<N_EDGES / TE, 256, 0, stream>>>(hb, ei, ef, wp, gb, cb, eidx, agg);
    col_stats<<<200, 256, 0, stream>>>(agg, stats);
    finalize_stats<<<1, 128, 0, stream>>>(stats, gamma, beta, scbi);
    out_softplus<<<(N_NODES * D / 4 + 255) / 256, 256, 0, stream>>>(h, agg, scbi, out);
}